// Round 13
// baseline (137.441 us; speedup 1.0000x reference)
//
#include <hip/hip_runtime.h>

// Problem constants (from reference)
constexpr int B = 8;
constexpr int N = 4096;
constexpr int E = 131072;     // 2^17
constexpr int C = 256;
constexpr int BN_TOT = B * N; // 32768

typedef __attribute__((ext_vector_type(8))) short s16x8;
typedef __attribute__((ext_vector_type(4))) float f32x4;

__device__ __forceinline__ unsigned short f2bf(float f) {
    unsigned u = __float_as_uint(f);
    unsigned r = (u + 0x7FFFu + ((u >> 16) & 1u)) >> 16;   // RNE
    return (unsigned short)r;
}
__device__ __forceinline__ float b2f(unsigned short u) {
    return __uint_as_float(((unsigned)u) << 16);
}
// unpack 2 packed bf16 (u32) -> 2 f32: low ch = q<<16, high ch = q & 0xFFFF0000
__device__ __forceinline__ void acc2(float2& a, unsigned q) {
    a.x += __uint_as_float(q << 16);
    a.y += __uint_as_float(q & 0xFFFF0000u);
}
__device__ __forceinline__ float2 unpk(unsigned q) {
    return make_float2(__uint_as_float(q << 16), __uint_as_float(q & 0xFFFF0000u));
}
__device__ __forceinline__ void accb(float2* acc, const uint4& f) {
    acc2(acc[0], f.x); acc2(acc[1], f.y); acc2(acc[2], f.z); acc2(acc[3], f.w);
}

// ---------------------------------------------------------------------------
// K1: per-block LDS histogram of edge destinations. 64 blocks per graph,
// 2048 edges each. LDS atomicAdd's return value IS the edge's local rank
// within (block, dst) -> rankp = dst | lr<<12 (lr < 2048 fits).
__global__ __launch_bounds__(1024) void hist_kernel(const int* __restrict__ ei,
                                                    int* __restrict__ parthist,
                                                    int* __restrict__ rankp) {
    __shared__ int lh[4096];
    int bid = blockIdx.x;          // 512
    int g = bid & 7;               // XCD-pinned graph
    int blk = bid >> 3;            // [0,64)
    int t = threadIdx.x;
#pragma unroll
    for (int i = 0; i < 4; ++i) lh[t + i * 1024] = 0;
    __syncthreads();
    const int* dsts = ei + (size_t)g * 2 * E + E + blk * 2048;
    int e0 = blk * 2048 + t;
    int d0 = dsts[t];
    int r0 = atomicAdd(&lh[d0], 1);
    rankp[(size_t)g * E + e0] = d0 | (r0 << 12);
    int d1 = dsts[t + 1024];
    int r1 = atomicAdd(&lh[d1], 1);
    rankp[(size_t)g * E + e0 + 1024] = d1 | (r1 << 12);
    __syncthreads();
    int* ph = parthist + (size_t)bid * 4096;
#pragma unroll
    for (int i = 0; i < 4; ++i) ph[t + i * 1024] = lh[t + i * 1024];
}

// ---------------------------------------------------------------------------
// K2: per-(graph,dst) prefix over the 64 block-partials. 32768 threads
// (128 blocks) -> full-GPU TLP for the serial 64-step column walk.
// (R11 lesson: fusing this into 8 blocks = 1% occupancy = +40 us.)
__global__ __launch_bounds__(256) void colsum_kernel(int* __restrict__ parthist,
                                                     int* __restrict__ counts) {
    int t = blockIdx.x * 256 + threadIdx.x;   // [0, 32768)
    int g = t >> 12;
    int dst = t & 4095;
    int run = 0;
    for (int j = 0; j < 64; ++j) {
        int* p = parthist + (size_t)(j * 8 + g) * 4096 + dst;
        int c = *p;
        *p = run;
        run += c;
    }
    counts[g * N + dst] = run;
}

// ---------------------------------------------------------------------------
// K3: per-graph exclusive scan of counts -> CSR offsets; dinv = rsqrt(deg+1)
__global__ __launch_bounds__(1024) void scan_kernel(const int* __restrict__ counts,
                                                    int* __restrict__ offs,
                                                    float* __restrict__ dinv) {
    __shared__ int lds[1024];
    int b = blockIdx.x, t = threadIdx.x;
    int base = b * N + t * 4;
    int c0 = counts[base + 0];
    int c1 = counts[base + 1];
    int c2 = counts[base + 2];
    int c3 = counts[base + 3];
    lds[t] = c0 + c1 + c2 + c3;
    __syncthreads();
    for (int s = 1; s < 1024; s <<= 1) {
        int v = 0;
        if (t >= s) v = lds[t - s];
        __syncthreads();
        lds[t] += v;
        __syncthreads();
    }
    int excl = (t == 0) ? 0 : lds[t - 1];
    int ob = b * (N + 1) + t * 4;
    offs[ob + 0] = excl;
    offs[ob + 1] = excl + c0;
    offs[ob + 2] = excl + c0 + c1;
    offs[ob + 3] = excl + c0 + c1 + c2;
    if (t == 1023) offs[b * (N + 1) + N] = lds[1023];
    dinv[base + 0] = rsqrtf((float)(c0 + 1));
    dinv[base + 1] = rsqrtf((float)(c1 + 1));
    dinv[base + 2] = rsqrtf((float)(c2 + 1));
    dinv[base + 3] = rsqrtf((float)(c3 + 1));
}

// ---------------------------------------------------------------------------
// K4 (mega): block-range dispatch of three independent post-scan jobs:
//   [0,8192)      xconv: y1 = dinv[row]*x (f32->bf16), XCD-pinned
//   [8192,12288)  fill : scatter edge srcs into CSR (atomic-free; slot =
//                        offs[dst] + parthist[blk][dst] + local rank)
//   [12288,12416) prep_w: W[K][N] f32 -> Wt[N][K] bf16 for both layers
__global__ __launch_bounds__(256) void mega_kernel(const int* __restrict__ ei,
                                                   const int* __restrict__ offs,
                                                   const int* __restrict__ rankp,
                                                   const int* __restrict__ parthist,
                                                   int* __restrict__ csr,
                                                   const float* __restrict__ x,
                                                   unsigned short* __restrict__ xb,
                                                   const float* __restrict__ dinv,
                                                   const float* __restrict__ W1,
                                                   const float* __restrict__ W2,
                                                   unsigned short* __restrict__ Wt1,
                                                   unsigned short* __restrict__ Wt2) {
    int bid = blockIdx.x;
    int tid = threadIdx.x;
    if (bid < 8192) {
        // --- xconv ---
        int g = bid & 7;
        int off = bid >> 3;                          // [0,1024)
        size_t base = (size_t)g * (N * C) + (size_t)off * 1024 + tid * 4;
        float dv = dinv[g * N + off * 4 + (tid >> 6)];
        float4 v = *(const float4*)(x + base);
        ushort4 o;
        o.x = f2bf(dv * v.x); o.y = f2bf(dv * v.y);
        o.z = f2bf(dv * v.z); o.w = f2bf(dv * v.w);
        *(ushort4*)(xb + base) = o;
    } else if (bid < 12288) {
        // --- fill ---
        int b2 = bid - 8192;
        int g = b2 & 7;
        int e = (b2 >> 3) * 256 + tid;
        int src = ei[(size_t)g * 2 * E + e];
        int pk = rankp[(size_t)g * E + e];
        int dst = pk & 4095;
        int lr = pk >> 12;
        int blk = e >> 11;
        int bb = parthist[(size_t)(blk * 8 + g) * 4096 + dst];
        csr[(size_t)g * E + offs[g * (N + 1) + dst] + bb + lr] = src;
    } else {
        // --- prep_w ---
        int f = (bid - 12288) * 256 + tid;           // [0, 32768)
        int w = f >> 14;                             // 0: W1, 1: W2
        int idx = f & 16383;
        int n = idx >> 6;
        int ln = idx & 63;
        const float* W = w ? W2 : W1;
        unsigned short* Wt = w ? Wt2 : Wt1;
#pragma unroll
        for (int i = 0; i < 4; ++i) {
            int k = ln + i * 64;
            Wt[n * 256 + k] = f2bf(W[k * 256 + n]);
        }
    }
}

// ---------------------------------------------------------------------------
// K5: norm-free aggregation, ONE WAVE PER NODE, LATENCY-PIPELINED:
//   out[b,v,:] = dinv[v] * ( y[b,v,:] + sum_{u->v} y[b,u,:] )
// Lanes 0-31 take even edges, 32-63 odd. Fast path (np<=32 pairs, >99.99% of
// Poisson(32) nodes): preload ALL batch indices up front (independent loads),
// then gather(b_{k+1}) is issued BEFORE acc(b_k) -- each acc's vmcnt wait is
// covered by a full batch of acc VALU, instead of eating a raw ~250cy L2
// latency per batch (the R12 structure's flaw). Static-indexed A/B register
// buffers (no scratch). Streaming fallback for np>32.
__global__ __launch_bounds__(64) void agg_sum(const unsigned short* __restrict__ in,
                                              unsigned short* __restrict__ out,
                                              const int* __restrict__ csr,
                                              const int* __restrict__ offs,
                                              const float* __restrict__ dinv) {
    int bid = blockIdx.x;                 // 32768
    int b = bid & 7;                      // XCD-pinned graph
    int v = bid >> 3;                     // [0,4096)
    int lane = threadIdx.x;               // [0,64)
    int half = lane >> 5;                 // 0: even edge of pair, 1: odd
    int hl = lane & 31;                   // channels [hl*8, hl*8+8)
    const unsigned short* inb = in + (size_t)b * (N * C);
    const char* base = (const char*)(inb + hl * 8);
    const int* cs2 = csr + (size_t)b * E + half;   // cs2[2*j] = edge (j,half)

    // all independent loads issued up-front
    uint4 xv = *(const uint4*)(inb + (size_t)v * C + hl * 8);
    float dv = dinv[b * N + v];
    int s = offs[b * (N + 1) + v];
    int e = offs[b * (N + 1) + v + 1];
    const int* ip0 = cs2 + s;

    float2 acc[4];
    if (half) {
        acc[0] = acc[1] = acc[2] = acc[3] = make_float2(0.f, 0.f);
    } else {
        acc[0] = unpk(xv.x); acc[1] = unpk(xv.y);
        acc[2] = unpk(xv.z); acc[3] = unpk(xv.w);
    }

    int np = (e - s) >> 1;               // edge pairs (wave-uniform)
    int nb = np >> 3;                    // full 8-pair batches
    int ip = 0;

    if (nb >= 1 && nb <= 4) {
        // ---- fast path: preload all indices, acc one batch behind ----
        int u0[8], u1[8], u2[8], u3[8];
        uint4 fA[8], fB[8];
#pragma unroll
        for (int j = 0; j < 8; ++j) u0[j] = ip0[2 * j];
        if (nb >= 2) {
#pragma unroll
            for (int j = 0; j < 8; ++j) u1[j] = ip0[2 * (8 + j)];
        }
        if (nb >= 3) {
#pragma unroll
            for (int j = 0; j < 8; ++j) u2[j] = ip0[2 * (16 + j)];
        }
        if (nb >= 4) {
#pragma unroll
            for (int j = 0; j < 8; ++j) u3[j] = ip0[2 * (24 + j)];
        }
#pragma unroll
        for (int j = 0; j < 8; ++j)
            fA[j] = *(const uint4*)(base + ((size_t)(unsigned)u0[j] << 9));
        if (nb >= 2) {
#pragma unroll
            for (int j = 0; j < 8; ++j)
                fB[j] = *(const uint4*)(base + ((size_t)(unsigned)u1[j] << 9));
        }
#pragma unroll
        for (int j = 0; j < 8; ++j) accb(acc, fA[j]);       // b0
        if (nb >= 3) {
#pragma unroll
            for (int j = 0; j < 8; ++j)
                fA[j] = *(const uint4*)(base + ((size_t)(unsigned)u2[j] << 9));
        }
        if (nb >= 2) {
#pragma unroll
            for (int j = 0; j < 8; ++j) accb(acc, fB[j]);   // b1
        }
        if (nb >= 4) {
#pragma unroll
            for (int j = 0; j < 8; ++j)
                fB[j] = *(const uint4*)(base + ((size_t)(unsigned)u3[j] << 9));
        }
        if (nb >= 3) {
#pragma unroll
            for (int j = 0; j < 8; ++j) accb(acc, fA[j]);   // b2
        }
        if (nb >= 4) {
#pragma unroll
            for (int j = 0; j < 8; ++j) accb(acc, fB[j]);   // b3
        }
        ip = nb * 8;
    } else if (nb > 4) {
        // ---- streaming fallback (rare: deg > ~65) ----
        int u[8];
#pragma unroll
        for (int j = 0; j < 8; ++j) u[j] = ip0[2 * j];
        for (; ip + 16 <= np; ip += 8) {
            uint4 f[8];
#pragma unroll
            for (int j = 0; j < 8; ++j)
                f[j] = *(const uint4*)(base + ((size_t)(unsigned)u[j] << 9));
#pragma unroll
            for (int j = 0; j < 8; ++j) u[j] = ip0[2 * (ip + 8 + j)];
#pragma unroll
            for (int j = 0; j < 8; ++j) accb(acc, f[j]);
        }
        {   // drain last preloaded batch
            uint4 f[8];
#pragma unroll
            for (int j = 0; j < 8; ++j)
                f[j] = *(const uint4*)(base + ((size_t)(unsigned)u[j] << 9));
#pragma unroll
            for (int j = 0; j < 8; ++j) accb(acc, f[j]);
            ip += 8;
        }
    }

    if (ip + 4 <= np) {                  // batched tail of 4 pairs
        int u[4];
#pragma unroll
        for (int j = 0; j < 4; ++j) u[j] = ip0[2 * (ip + j)];
        uint4 f[4];
#pragma unroll
        for (int j = 0; j < 4; ++j)
            f[j] = *(const uint4*)(base + ((size_t)(unsigned)u[j] << 9));
#pragma unroll
        for (int j = 0; j < 4; ++j) accb(acc, f[j]);
        ip += 4;
    }
    for (; ip < np; ++ip) {
        int u = ip0[2 * ip];
        uint4 f = *(const uint4*)(base + ((size_t)(unsigned)u << 9));
        accb(acc, f);
    }
    if (((e - s) & 1) && !half) {        // odd tail edge: lower half only
        int u = ip0[2 * np];             // = cs[e-1] (half==0)
        uint4 f = *(const uint4*)(base + ((size_t)(unsigned)u << 9));
        accb(acc, f);
    }

    // combine halves
#pragma unroll
    for (int c = 0; c < 4; ++c) {
        acc[c].x += __shfl_xor(acc[c].x, 32, 64);
        acc[c].y += __shfl_xor(acc[c].y, 32, 64);
    }

    if (!half) {
        ushort4 o01, o23;
        o01.x = f2bf(dv * acc[0].x); o01.y = f2bf(dv * acc[0].y);
        o01.z = f2bf(dv * acc[1].x); o01.w = f2bf(dv * acc[1].y);
        o23.x = f2bf(dv * acc[2].x); o23.y = f2bf(dv * acc[2].y);
        o23.z = f2bf(dv * acc[3].x); o23.w = f2bf(dv * acc[3].y);
        unsigned short* op = out + ((size_t)b * N + v) * C + hl * 8;
        *(ushort4*)(op) = o01;
        *(ushort4*)(op + 4) = o23;
    }
}

// ---------------------------------------------------------------------------
// K6: bf16 MFMA GEMM with async stage split. Single 24 KB buffer -> 4 blocks/CU.
// Cout[M,256] = A[M,256]@W[256,256] (+bias, opt ReLU, opt row-scale by dinv).
// A bf16 row-major; Wt bf16 TRANSPOSED [N][K]. LDS XOR-swizzled.
// C/D layout (HW-verified): col = lane&15, row = (lane>>4)*4 + reg.
template <bool RELU, bool BF16OUT, bool SCALE>
__global__ __launch_bounds__(256) void gemm_mfma(const unsigned short* __restrict__ A,
                                                 const unsigned short* __restrict__ Wt,
                                                 const float* __restrict__ bias,
                                                 const float* __restrict__ dinv,
                                                 void* __restrict__ Cout) {
    __shared__ __align__(16) char lds[24576];
    char* AsB = lds;            // 16 KB: [128 m][64 k] bf16, swizzled
    char* WsB = lds + 16384;    //  8 KB: [64 n][64 k] bf16, swizzled

    int tid = threadIdx.x;
    int bid = blockIdx.x;
    int g = bid & 7;                 // XCD-pinned graph
    int i = bid >> 3;                // [0,128)
    int mloc = i >> 2;               // [0,32)
    int nb = i & 3;                  // [0,4)
    int bm = g * 4096 + mloc * 128;
    int bn = nb * 64;

    const int l = tid & 63;
    const int w = tid >> 6;
    const int lr = l & 15;
    const int lg = l >> 4;

    const int arow = tid >> 3, aslot = tid & 7;
    const int wrow = tid >> 3, wslot = tid & 7;

    f32x4 acc[2][4] = {};

    // ---- prologue: stage kc = 0 synchronously ----
#pragma unroll
    for (int c = 0; c < 4; ++c) {
        int row = arow + c * 32;
        s16x8 vv = *(const s16x8*)(A + (size_t)(bm + row) * 256 + aslot * 8);
        *(s16x8*)(AsB + row * 128 + ((aslot * 16) ^ ((row & 7) << 4))) = vv;
    }
#pragma unroll
    for (int c = 0; c < 2; ++c) {
        int r = wrow + c * 32;
        s16x8 vv = *(const s16x8*)(Wt + (size_t)(bn + r) * 256 + wslot * 8);
        *(s16x8*)(WsB + r * 128 + ((wslot * 16) ^ ((r & 7) << 4))) = vv;
    }
    __syncthreads();

#pragma unroll
    for (int kc = 0; kc < 4; ++kc) {
        s16x8 pa0, pa1, pa2, pa3, pw0, pw1;
        if (kc < 3) {
            int ko = (kc + 1) * 64;
            pa0 = *(const s16x8*)(A + (size_t)(bm + arow +  0) * 256 + ko + aslot * 8);
            pa1 = *(const s16x8*)(A + (size_t)(bm + arow + 32) * 256 + ko + aslot * 8);
            pa2 = *(const s16x8*)(A + (size_t)(bm + arow + 64) * 256 + ko + aslot * 8);
            pa3 = *(const s16x8*)(A + (size_t)(bm + arow + 96) * 256 + ko + aslot * 8);
            pw0 = *(const s16x8*)(Wt + (size_t)(bn + wrow +  0) * 256 + ko + wslot * 8);
            pw1 = *(const s16x8*)(Wt + (size_t)(bn + wrow + 32) * 256 + ko + wslot * 8);
        }

#pragma unroll
        for (int ks = 0; ks < 2; ++ks) {
            s16x8 af[2];
#pragma unroll
            for (int m = 0; m < 2; ++m) {
                int row = w * 32 + m * 16 + lr;
                int bir = ks * 64 + lg * 16;
                af[m] = *(const s16x8*)(AsB + row * 128 + (bir ^ ((row & 7) << 4)));
            }
            s16x8 wf[4];
#pragma unroll
            for (int n = 0; n < 4; ++n) {
                int cidx = n * 16 + lr;
                int bir = ks * 64 + lg * 16;
                wf[n] = *(const s16x8*)(WsB + cidx * 128 + (bir ^ ((cidx & 7) << 4)));
            }
#pragma unroll
            for (int m = 0; m < 2; ++m)
#pragma unroll
                for (int n = 0; n < 4; ++n)
                    acc[m][n] = __builtin_amdgcn_mfma_f32_16x16x32_bf16(af[m], wf[n], acc[m][n], 0, 0, 0);
        }
        __syncthreads();

        if (kc < 3) {
            {
                int row = arow;
                *(s16x8*)(AsB + row * 128 + ((aslot * 16) ^ ((row & 7) << 4))) = pa0;
                row = arow + 32;
                *(s16x8*)(AsB + row * 128 + ((aslot * 16) ^ ((row & 7) << 4))) = pa1;
                row = arow + 64;
                *(s16x8*)(AsB + row * 128 + ((aslot * 16) ^ ((row & 7) << 4))) = pa2;
                row = arow + 96;
                *(s16x8*)(AsB + row * 128 + ((aslot * 16) ^ ((row & 7) << 4))) = pa3;
            }
            {
                int r = wrow;
                *(s16x8*)(WsB + r * 128 + ((wslot * 16) ^ ((r & 7) << 4))) = pw0;
                r = wrow + 32;
                *(s16x8*)(WsB + r * 128 + ((wslot * 16) ^ ((r & 7) << 4))) = pw1;
            }
            __syncthreads();
        }
    }

    // Epilogue: D col = lane&15, row = (lane>>4)*4 + reg
#pragma unroll
    for (int m = 0; m < 2; ++m) {
        int base_row = bm + w * 32 + m * 16 + lg * 4;
        float4 dv4 = make_float4(1.f, 1.f, 1.f, 1.f);
        if (SCALE) dv4 = *(const float4*)(dinv + base_row);
        float dvr[4] = {dv4.x, dv4.y, dv4.z, dv4.w};
#pragma unroll
        for (int n = 0; n < 4; ++n) {
            int col = bn + n * 16 + lr;
            float bb = bias[col];
            f32x4 v = acc[m][n];
#pragma unroll
            for (int r = 0; r < 4; ++r) {
                float o = v[r] + bb;
                if (RELU) o = fmaxf(o, 0.f);
                if (SCALE) o *= dvr[r];
                if (BF16OUT)
                    ((unsigned short*)Cout)[(size_t)(base_row + r) * 256 + col] = f2bf(o);
                else
                    ((float*)Cout)[(size_t)(base_row + r) * 256 + col] = o;
            }
        }
    }
}

// ---------------------------------------------------------------------------
extern "C" void kernel_launch(void* const* d_in, const int* in_sizes, int n_in,
                              void* d_out, int out_size, void* d_ws, size_t ws_size,
                              hipStream_t stream) {
    const float* x  = (const float*)d_in[0];
    const int*   ei = (const int*)d_in[1];
    const float* W1 = (const float*)d_in[2];
    const float* b1 = (const float*)d_in[3];
    const float* W2 = (const float*)d_in[4];
    const float* b2 = (const float*)d_in[5];
    float* out = (float*)d_out;

    char* w = (char*)d_ws;
    float* dinv            = (float*)(w + 0x0);        // 128 KB
    int*   counts          = (int*)  (w + 0x20000);    // 128 KB
    int*   offs            = (int*)  (w + 0x60000);    // ~128 KB
    int*   csr             = (int*)  (w + 0x90000);    // 4 MB
    unsigned short* Wt1    = (unsigned short*)(w + 0x4A0000);   // 128 KB
    unsigned short* Wt2    = (unsigned short*)(w + 0x4C0000);   // 128 KB
    unsigned short* xb     = (unsigned short*)(w + 0x500000);   // 16 MB (y1)
    unsigned short* bufA   = (unsigned short*)(w + 0x1500000);  // 16 MB
    unsigned short* bufB   = (unsigned short*)(w + 0x2500000);  // 16 MB (y2)
    unsigned short* bufC   = (unsigned short*)(w + 0x3500000);  // 16 MB (ends 0x4500000)
    int*   rankp           = (int*)bufC;   // alias: dead before bufC is written (agg2)
    int*   parthist        = (int*)bufA;   // alias: 8 MB, dead before bufA is written (agg1)

    hist_kernel<<<512, 1024, 0, stream>>>(ei, parthist, rankp);
    colsum_kernel<<<128, 256, 0, stream>>>(parthist, counts);
    scan_kernel<<<B, 1024, 0, stream>>>(counts, offs, dinv);
    mega_kernel<<<12416, 256, 0, stream>>>(ei, offs, rankp, parthist, csr,
                                           x, xb, dinv, W1, W2, Wt1, Wt2);

    // layer 1: agg(y1) -> bufA ; y2 = dinv*relu(bufA@W1+b1) -> bufB
    agg_sum<<<32768, 64, 0, stream>>>(xb, bufA, csr, offs, dinv);
    gemm_mfma<true, true, true><<<1024, 256, 0, stream>>>(bufA, Wt1, b1, dinv, bufB);
    // layer 2: agg(y2) -> bufC ; bufC@W2+b2 -> out (f32)
    agg_sum<<<32768, 64, 0, stream>>>(bufB, bufC, csr, offs, dinv);
    gemm_mfma<false, false, false><<<1024, 256, 0, stream>>>(bufC, Wt2, b2, nullptr, out);
}

// Round 14
// 131.766 us; speedup vs baseline: 1.0431x; 1.0431x over previous
//
#include <hip/hip_runtime.h>

// Problem constants (from reference)
constexpr int B = 8;
constexpr int N = 4096;
constexpr int E = 131072;     // 2^17
constexpr int C = 256;
constexpr int BN_TOT = B * N; // 32768

typedef __attribute__((ext_vector_type(8))) short s16x8;
typedef __attribute__((ext_vector_type(4))) float f32x4;

__device__ __forceinline__ unsigned short f2bf(float f) {
    unsigned u = __float_as_uint(f);
    unsigned r = (u + 0x7FFFu + ((u >> 16) & 1u)) >> 16;   // RNE
    return (unsigned short)r;
}
__device__ __forceinline__ float b2f(unsigned short u) {
    return __uint_as_float(((unsigned)u) << 16);
}
// unpack 2 packed bf16 (u32) -> 2 f32: low ch = q<<16, high ch = q & 0xFFFF0000
__device__ __forceinline__ void acc2(float2& a, unsigned q) {
    a.x += __uint_as_float(q << 16);
    a.y += __uint_as_float(q & 0xFFFF0000u);
}
__device__ __forceinline__ float2 unpk(unsigned q) {
    return make_float2(__uint_as_float(q << 16), __uint_as_float(q & 0xFFFF0000u));
}
__device__ __forceinline__ void accb(float2* acc, const uint4& f) {
    acc2(acc[0], f.x); acc2(acc[1], f.y); acc2(acc[2], f.z); acc2(acc[3], f.w);
}

// ---------------------------------------------------------------------------
// K1: per-block LDS histogram of edge destinations. 64 blocks per graph,
// 2048 edges each. LDS atomicAdd's return value IS the edge's local rank
// within (block, dst) -> rankp = dst | lr<<12 (lr < 2048 fits).
__global__ __launch_bounds__(1024) void hist_kernel(const int* __restrict__ ei,
                                                    int* __restrict__ parthist,
                                                    int* __restrict__ rankp) {
    __shared__ int lh[4096];
    int bid = blockIdx.x;          // 512
    int g = bid & 7;               // XCD-pinned graph
    int blk = bid >> 3;            // [0,64)
    int t = threadIdx.x;
#pragma unroll
    for (int i = 0; i < 4; ++i) lh[t + i * 1024] = 0;
    __syncthreads();
    const int* dsts = ei + (size_t)g * 2 * E + E + blk * 2048;
    int e0 = blk * 2048 + t;
    int d0 = dsts[t];
    int r0 = atomicAdd(&lh[d0], 1);
    rankp[(size_t)g * E + e0] = d0 | (r0 << 12);
    int d1 = dsts[t + 1024];
    int r1 = atomicAdd(&lh[d1], 1);
    rankp[(size_t)g * E + e0 + 1024] = d1 | (r1 << 12);
    __syncthreads();
    int* ph = parthist + (size_t)bid * 4096;
#pragma unroll
    for (int i = 0; i < 4; ++i) ph[t + i * 1024] = lh[t + i * 1024];
}

// ---------------------------------------------------------------------------
// K2: per-(graph,dst) prefix over the 64 block-partials. 32768 threads
// (128 blocks) -> full-GPU TLP for the serial 64-step column walk.
// (R11 lesson: fusing this into 8 blocks = 1% occupancy = +40 us.)
__global__ __launch_bounds__(256) void colsum_kernel(int* __restrict__ parthist,
                                                     int* __restrict__ counts) {
    int t = blockIdx.x * 256 + threadIdx.x;   // [0, 32768)
    int g = t >> 12;
    int dst = t & 4095;
    int run = 0;
    for (int j = 0; j < 64; ++j) {
        int* p = parthist + (size_t)(j * 8 + g) * 4096 + dst;
        int c = *p;
        *p = run;
        run += c;
    }
    counts[g * N + dst] = run;
}

// ---------------------------------------------------------------------------
// K3: per-graph exclusive scan of counts -> CSR offsets; dinv = rsqrt(deg+1)
__global__ __launch_bounds__(1024) void scan_kernel(const int* __restrict__ counts,
                                                    int* __restrict__ offs,
                                                    float* __restrict__ dinv) {
    __shared__ int lds[1024];
    int b = blockIdx.x, t = threadIdx.x;
    int base = b * N + t * 4;
    int c0 = counts[base + 0];
    int c1 = counts[base + 1];
    int c2 = counts[base + 2];
    int c3 = counts[base + 3];
    lds[t] = c0 + c1 + c2 + c3;
    __syncthreads();
    for (int s = 1; s < 1024; s <<= 1) {
        int v = 0;
        if (t >= s) v = lds[t - s];
        __syncthreads();
        lds[t] += v;
        __syncthreads();
    }
    int excl = (t == 0) ? 0 : lds[t - 1];
    int ob = b * (N + 1) + t * 4;
    offs[ob + 0] = excl;
    offs[ob + 1] = excl + c0;
    offs[ob + 2] = excl + c0 + c1;
    offs[ob + 3] = excl + c0 + c1 + c2;
    if (t == 1023) offs[b * (N + 1) + N] = lds[1023];
    dinv[base + 0] = rsqrtf((float)(c0 + 1));
    dinv[base + 1] = rsqrtf((float)(c1 + 1));
    dinv[base + 2] = rsqrtf((float)(c2 + 1));
    dinv[base + 3] = rsqrtf((float)(c3 + 1));
}

// ---------------------------------------------------------------------------
// K4 (mega): block-range dispatch of three independent post-scan jobs:
//   [0,8192)      xconv: y1 = dinv[row]*x (f32->bf16), XCD-pinned
//   [8192,12288)  fill : scatter edge srcs into CSR (atomic-free; slot =
//                        offs[dst] + parthist[blk][dst] + local rank)
//   [12288,12416) prep_w: W[K][N] f32 -> Wt[N][K] bf16 for both layers
__global__ __launch_bounds__(256) void mega_kernel(const int* __restrict__ ei,
                                                   const int* __restrict__ offs,
                                                   const int* __restrict__ rankp,
                                                   const int* __restrict__ parthist,
                                                   int* __restrict__ csr,
                                                   const float* __restrict__ x,
                                                   unsigned short* __restrict__ xb,
                                                   const float* __restrict__ dinv,
                                                   const float* __restrict__ W1,
                                                   const float* __restrict__ W2,
                                                   unsigned short* __restrict__ Wt1,
                                                   unsigned short* __restrict__ Wt2) {
    int bid = blockIdx.x;
    int tid = threadIdx.x;
    if (bid < 8192) {
        // --- xconv ---
        int g = bid & 7;
        int off = bid >> 3;                          // [0,1024)
        size_t base = (size_t)g * (N * C) + (size_t)off * 1024 + tid * 4;
        float dv = dinv[g * N + off * 4 + (tid >> 6)];
        float4 v = *(const float4*)(x + base);
        ushort4 o;
        o.x = f2bf(dv * v.x); o.y = f2bf(dv * v.y);
        o.z = f2bf(dv * v.z); o.w = f2bf(dv * v.w);
        *(ushort4*)(xb + base) = o;
    } else if (bid < 12288) {
        // --- fill ---
        int b2 = bid - 8192;
        int g = b2 & 7;
        int e = (b2 >> 3) * 256 + tid;
        int src = ei[(size_t)g * 2 * E + e];
        int pk = rankp[(size_t)g * E + e];
        int dst = pk & 4095;
        int lr = pk >> 12;
        int blk = e >> 11;
        int bb = parthist[(size_t)(blk * 8 + g) * 4096 + dst];
        csr[(size_t)g * E + offs[g * (N + 1) + dst] + bb + lr] = src;
    } else {
        // --- prep_w ---
        int f = (bid - 12288) * 256 + tid;           // [0, 32768)
        int w = f >> 14;                             // 0: W1, 1: W2
        int idx = f & 16383;
        int n = idx >> 6;
        int ln = idx & 63;
        const float* W = w ? W2 : W1;
        unsigned short* Wt = w ? Wt2 : Wt1;
#pragma unroll
        for (int i = 0; i < 4; ++i) {
            int k = ln + i * 64;
            Wt[n * 256 + k] = f2bf(W[k * 256 + n]);
        }
    }
}

// ---------------------------------------------------------------------------
// K5: norm-free aggregation, 4 WAVES/BLOCK, EACH WAVE OWNS 8 CONSECUTIVE
// NODES of one graph (wave-independent strips):
//   out[b,v,:] = dinv[v] * ( y[b,v,:] + sum_{u->v} y[b,u,:] )
// - 256-thr blocks: occupancy no longer workgroup-slot-capped (R13 lesson:
//   64-thr WGs pinned occupancy at 25%).
// - per-wave 8-node strip: block retires on max of 4 sums-of-8-Poisson(32)
//   degrees (sigma/mu ~6%) instead of max of 4 single degrees (~25% waste).
// Lanes 0-31 take even edges, 32-63 odd; CSR pointer pre-offset by `half`;
// lean R12 streaming 8-pair pipeline (VGPR stays ~40).
__global__ __launch_bounds__(256) void agg_sum(const unsigned short* __restrict__ in,
                                               unsigned short* __restrict__ out,
                                               const int* __restrict__ csr,
                                               const int* __restrict__ offs,
                                               const float* __restrict__ dinv) {
    int bid = blockIdx.x;                 // 1024
    int g = bid & 7;                      // XCD-pinned graph
    int w = threadIdx.x >> 6;             // wave [0,4)
    int lane = threadIdx.x & 63;
    int half = lane >> 5;                 // 0: even edge of pair, 1: odd
    int hl = lane & 31;                   // channels [hl*8, hl*8+8)
    const unsigned short* inb = in + (size_t)g * (N * C);
    const char* base = (const char*)(inb + hl * 8);
    const int* cs2 = csr + (size_t)g * E + half;   // cs2[2*j] = edge (j,half)
    const int* ofg = offs + g * (N + 1);

    int v0 = (bid >> 3) * 32 + w * 8;     // this wave's 8-node strip

    for (int k = 0; k < 8; ++k) {
        int v = v0 + k;
        float dv = dinv[g * N + v];       // hoisted
        int s = ofg[v];
        int e = ofg[v + 1];
        const int* ip0 = cs2 + s;

        float2 acc[4];
        {   // self-loop term: lower half only
            uint4 xv = *(const uint4*)(inb + (size_t)v * C + hl * 8);
            if (half) {
                acc[0] = acc[1] = acc[2] = acc[3] = make_float2(0.f, 0.f);
            } else {
                acc[0] = unpk(xv.x); acc[1] = unpk(xv.y);
                acc[2] = unpk(xv.z); acc[3] = unpk(xv.w);
            }
        }

        int np = (e - s) >> 1;           // edge pairs
        int ip = 0;
        if (np >= 8) {
            int u[8];
#pragma unroll
            for (int j = 0; j < 8; ++j) u[j] = ip0[2 * j];
            for (; ip + 16 <= np; ip += 8) {
                uint4 f[8];
#pragma unroll
                for (int j = 0; j < 8; ++j)
                    f[j] = *(const uint4*)(base + ((size_t)(unsigned)u[j] << 9));
#pragma unroll
                for (int j = 0; j < 8; ++j) u[j] = ip0[2 * (ip + 8 + j)];
#pragma unroll
                for (int j = 0; j < 8; ++j) accb(acc, f[j]);
            }
            {   // drain last preloaded batch
                uint4 f[8];
#pragma unroll
                for (int j = 0; j < 8; ++j)
                    f[j] = *(const uint4*)(base + ((size_t)(unsigned)u[j] << 9));
#pragma unroll
                for (int j = 0; j < 8; ++j) accb(acc, f[j]);
                ip += 8;
            }
        }
        if (ip + 4 <= np) {              // batched tail of 4 pairs
            int u[4];
#pragma unroll
            for (int j = 0; j < 4; ++j) u[j] = ip0[2 * (ip + j)];
            uint4 f[4];
#pragma unroll
            for (int j = 0; j < 4; ++j)
                f[j] = *(const uint4*)(base + ((size_t)(unsigned)u[j] << 9));
#pragma unroll
            for (int j = 0; j < 4; ++j) accb(acc, f[j]);
            ip += 4;
        }
        for (; ip < np; ++ip) {
            int u = ip0[2 * ip];
            uint4 f = *(const uint4*)(base + ((size_t)(unsigned)u << 9));
            accb(acc, f);
        }
        if (((e - s) & 1) && !half) {    // odd tail edge: lower half only
            int u = ip0[2 * np];         // = cs[e-1] (half==0)
            uint4 f = *(const uint4*)(base + ((size_t)(unsigned)u << 9));
            accb(acc, f);
        }

        // combine halves
#pragma unroll
        for (int c = 0; c < 4; ++c) {
            acc[c].x += __shfl_xor(acc[c].x, 32, 64);
            acc[c].y += __shfl_xor(acc[c].y, 32, 64);
        }

        if (!half) {
            ushort4 o01, o23;
            o01.x = f2bf(dv * acc[0].x); o01.y = f2bf(dv * acc[0].y);
            o01.z = f2bf(dv * acc[1].x); o01.w = f2bf(dv * acc[1].y);
            o23.x = f2bf(dv * acc[2].x); o23.y = f2bf(dv * acc[2].y);
            o23.z = f2bf(dv * acc[3].x); o23.w = f2bf(dv * acc[3].y);
            unsigned short* op = out + ((size_t)g * N + v) * C + hl * 8;
            *(ushort4*)(op) = o01;
            *(ushort4*)(op + 4) = o23;
        }
    }
}

// ---------------------------------------------------------------------------
// K6: bf16 MFMA GEMM with async stage split. Single 24 KB buffer -> 4 blocks/CU.
// Cout[M,256] = A[M,256]@W[256,256] (+bias, opt ReLU, opt row-scale by dinv).
// A bf16 row-major; Wt bf16 TRANSPOSED [N][K]. LDS XOR-swizzled.
// C/D layout (HW-verified): col = lane&15, row = (lane>>4)*4 + reg.
template <bool RELU, bool BF16OUT, bool SCALE>
__global__ __launch_bounds__(256) void gemm_mfma(const unsigned short* __restrict__ A,
                                                 const unsigned short* __restrict__ Wt,
                                                 const float* __restrict__ bias,
                                                 const float* __restrict__ dinv,
                                                 void* __restrict__ Cout) {
    __shared__ __align__(16) char lds[24576];
    char* AsB = lds;            // 16 KB: [128 m][64 k] bf16, swizzled
    char* WsB = lds + 16384;    //  8 KB: [64 n][64 k] bf16, swizzled

    int tid = threadIdx.x;
    int bid = blockIdx.x;
    int g = bid & 7;                 // XCD-pinned graph
    int i = bid >> 3;                // [0,128)
    int mloc = i >> 2;               // [0,32)
    int nb = i & 3;                  // [0,4)
    int bm = g * 4096 + mloc * 128;
    int bn = nb * 64;

    const int l = tid & 63;
    const int w = tid >> 6;
    const int lr = l & 15;
    const int lg = l >> 4;

    const int arow = tid >> 3, aslot = tid & 7;
    const int wrow = tid >> 3, wslot = tid & 7;

    f32x4 acc[2][4] = {};

    // ---- prologue: stage kc = 0 synchronously ----
#pragma unroll
    for (int c = 0; c < 4; ++c) {
        int row = arow + c * 32;
        s16x8 vv = *(const s16x8*)(A + (size_t)(bm + row) * 256 + aslot * 8);
        *(s16x8*)(AsB + row * 128 + ((aslot * 16) ^ ((row & 7) << 4))) = vv;
    }
#pragma unroll
    for (int c = 0; c < 2; ++c) {
        int r = wrow + c * 32;
        s16x8 vv = *(const s16x8*)(Wt + (size_t)(bn + r) * 256 + wslot * 8);
        *(s16x8*)(WsB + r * 128 + ((wslot * 16) ^ ((r & 7) << 4))) = vv;
    }
    __syncthreads();

#pragma unroll
    for (int kc = 0; kc < 4; ++kc) {
        s16x8 pa0, pa1, pa2, pa3, pw0, pw1;
        if (kc < 3) {
            int ko = (kc + 1) * 64;
            pa0 = *(const s16x8*)(A + (size_t)(bm + arow +  0) * 256 + ko + aslot * 8);
            pa1 = *(const s16x8*)(A + (size_t)(bm + arow + 32) * 256 + ko + aslot * 8);
            pa2 = *(const s16x8*)(A + (size_t)(bm + arow + 64) * 256 + ko + aslot * 8);
            pa3 = *(const s16x8*)(A + (size_t)(bm + arow + 96) * 256 + ko + aslot * 8);
            pw0 = *(const s16x8*)(Wt + (size_t)(bn + wrow +  0) * 256 + ko + wslot * 8);
            pw1 = *(const s16x8*)(Wt + (size_t)(bn + wrow + 32) * 256 + ko + wslot * 8);
        }

#pragma unroll
        for (int ks = 0; ks < 2; ++ks) {
            s16x8 af[2];
#pragma unroll
            for (int m = 0; m < 2; ++m) {
                int row = w * 32 + m * 16 + lr;
                int bir = ks * 64 + lg * 16;
                af[m] = *(const s16x8*)(AsB + row * 128 + (bir ^ ((row & 7) << 4)));
            }
            s16x8 wf[4];
#pragma unroll
            for (int n = 0; n < 4; ++n) {
                int cidx = n * 16 + lr;
                int bir = ks * 64 + lg * 16;
                wf[n] = *(const s16x8*)(WsB + cidx * 128 + (bir ^ ((cidx & 7) << 4)));
            }
#pragma unroll
            for (int m = 0; m < 2; ++m)
#pragma unroll
                for (int n = 0; n < 4; ++n)
                    acc[m][n] = __builtin_amdgcn_mfma_f32_16x16x32_bf16(af[m], wf[n], acc[m][n], 0, 0, 0);
        }
        __syncthreads();

        if (kc < 3) {
            {
                int row = arow;
                *(s16x8*)(AsB + row * 128 + ((aslot * 16) ^ ((row & 7) << 4))) = pa0;
                row = arow + 32;
                *(s16x8*)(AsB + row * 128 + ((aslot * 16) ^ ((row & 7) << 4))) = pa1;
                row = arow + 64;
                *(s16x8*)(AsB + row * 128 + ((aslot * 16) ^ ((row & 7) << 4))) = pa2;
                row = arow + 96;
                *(s16x8*)(AsB + row * 128 + ((aslot * 16) ^ ((row & 7) << 4))) = pa3;
            }
            {
                int r = wrow;
                *(s16x8*)(WsB + r * 128 + ((wslot * 16) ^ ((r & 7) << 4))) = pw0;
                r = wrow + 32;
                *(s16x8*)(WsB + r * 128 + ((wslot * 16) ^ ((r & 7) << 4))) = pw1;
            }
            __syncthreads();
        }
    }

    // Epilogue: D col = lane&15, row = (lane>>4)*4 + reg
#pragma unroll
    for (int m = 0; m < 2; ++m) {
        int base_row = bm + w * 32 + m * 16 + lg * 4;
        float4 dv4 = make_float4(1.f, 1.f, 1.f, 1.f);
        if (SCALE) dv4 = *(const float4*)(dinv + base_row);
        float dvr[4] = {dv4.x, dv4.y, dv4.z, dv4.w};
#pragma unroll
        for (int n = 0; n < 4; ++n) {
            int col = bn + n * 16 + lr;
            float bb = bias[col];
            f32x4 v = acc[m][n];
#pragma unroll
            for (int r = 0; r < 4; ++r) {
                float o = v[r] + bb;
                if (RELU) o = fmaxf(o, 0.f);
                if (SCALE) o *= dvr[r];
                if (BF16OUT)
                    ((unsigned short*)Cout)[(size_t)(base_row + r) * 256 + col] = f2bf(o);
                else
                    ((float*)Cout)[(size_t)(base_row + r) * 256 + col] = o;
            }
        }
    }
}

// ---------------------------------------------------------------------------
extern "C" void kernel_launch(void* const* d_in, const int* in_sizes, int n_in,
                              void* d_out, int out_size, void* d_ws, size_t ws_size,
                              hipStream_t stream) {
    const float* x  = (const float*)d_in[0];
    const int*   ei = (const int*)d_in[1];
    const float* W1 = (const float*)d_in[2];
    const float* b1 = (const float*)d_in[3];
    const float* W2 = (const float*)d_in[4];
    const float* b2 = (const float*)d_in[5];
    float* out = (float*)d_out;

    char* w = (char*)d_ws;
    float* dinv            = (float*)(w + 0x0);        // 128 KB
    int*   counts          = (int*)  (w + 0x20000);    // 128 KB
    int*   offs            = (int*)  (w + 0x60000);    // ~128 KB
    int*   csr             = (int*)  (w + 0x90000);    // 4 MB
    unsigned short* Wt1    = (unsigned short*)(w + 0x4A0000);   // 128 KB
    unsigned short* Wt2    = (unsigned short*)(w + 0x4C0000);   // 128 KB
    unsigned short* xb     = (unsigned short*)(w + 0x500000);   // 16 MB (y1)
    unsigned short* bufA   = (unsigned short*)(w + 0x1500000);  // 16 MB
    unsigned short* bufB   = (unsigned short*)(w + 0x2500000);  // 16 MB (y2)
    unsigned short* bufC   = (unsigned short*)(w + 0x3500000);  // 16 MB (ends 0x4500000)
    int*   rankp           = (int*)bufC;   // alias: dead before bufC is written (agg2)
    int*   parthist        = (int*)bufA;   // alias: 8 MB, dead before bufA is written (agg1)

    hist_kernel<<<512, 1024, 0, stream>>>(ei, parthist, rankp);
    colsum_kernel<<<128, 256, 0, stream>>>(parthist, counts);
    scan_kernel<<<B, 1024, 0, stream>>>(counts, offs, dinv);
    mega_kernel<<<12416, 256, 0, stream>>>(ei, offs, rankp, parthist, csr,
                                           x, xb, dinv, W1, W2, Wt1, Wt2);

    // layer 1: agg(y1) -> bufA ; y2 = dinv*relu(bufA@W1+b1) -> bufB
    agg_sum<<<1024, 256, 0, stream>>>(xb, bufA, csr, offs, dinv);
    gemm_mfma<true, true, true><<<1024, 256, 0, stream>>>(bufA, Wt1, b1, dinv, bufB);
    // layer 2: agg(y2) -> bufC ; bufC@W2+b2 -> out (f32)
    agg_sum<<<1024, 256, 0, stream>>>(bufB, bufC, csr, offs, dinv);
    gemm_mfma<false, false, false><<<1024, 256, 0, stream>>>(bufC, Wt2, b2, nullptr, out);
}

// Round 15
// 129.322 us; speedup vs baseline: 1.0628x; 1.0189x over previous
//
#include <hip/hip_runtime.h>

// Problem constants (from reference)
constexpr int B = 8;
constexpr int N = 4096;
constexpr int E = 131072;     // 2^17
constexpr int C = 256;
constexpr int BN_TOT = B * N; // 32768

typedef __attribute__((ext_vector_type(8))) short s16x8;
typedef __attribute__((ext_vector_type(4))) float f32x4;

__device__ __forceinline__ unsigned short f2bf(float f) {
    unsigned u = __float_as_uint(f);
    unsigned r = (u + 0x7FFFu + ((u >> 16) & 1u)) >> 16;   // RNE
    return (unsigned short)r;
}
__device__ __forceinline__ float b2f(unsigned short u) {
    return __uint_as_float(((unsigned)u) << 16);
}
// unpack 2 packed bf16 (u32) -> 2 f32: low ch = q<<16, high ch = q & 0xFFFF0000
__device__ __forceinline__ void acc2(float2& a, unsigned q) {
    a.x += __uint_as_float(q << 16);
    a.y += __uint_as_float(q & 0xFFFF0000u);
}
__device__ __forceinline__ float2 unpk(unsigned q) {
    return make_float2(__uint_as_float(q << 16), __uint_as_float(q & 0xFFFF0000u));
}
__device__ __forceinline__ void accb(float2* acc, const uint4& f) {
    acc2(acc[0], f.x); acc2(acc[1], f.y); acc2(acc[2], f.z); acc2(acc[3], f.w);
}

// ---------------------------------------------------------------------------
// K1: per-block LDS histogram of edge destinations. 64 blocks per graph,
// 2048 edges each. LDS atomicAdd's return value IS the edge's local rank
// within (block, dst) -> rankp = dst | lr<<12 (lr < 2048 fits).
__global__ __launch_bounds__(1024) void hist_kernel(const int* __restrict__ ei,
                                                    int* __restrict__ parthist,
                                                    int* __restrict__ rankp) {
    __shared__ int lh[4096];
    int bid = blockIdx.x;          // 512
    int g = bid & 7;               // XCD-pinned graph
    int blk = bid >> 3;            // [0,64)
    int t = threadIdx.x;
#pragma unroll
    for (int i = 0; i < 4; ++i) lh[t + i * 1024] = 0;
    __syncthreads();
    const int* dsts = ei + (size_t)g * 2 * E + E + blk * 2048;
    int e0 = blk * 2048 + t;
    int d0 = dsts[t];
    int r0 = atomicAdd(&lh[d0], 1);
    rankp[(size_t)g * E + e0] = d0 | (r0 << 12);
    int d1 = dsts[t + 1024];
    int r1 = atomicAdd(&lh[d1], 1);
    rankp[(size_t)g * E + e0 + 1024] = d1 | (r1 << 12);
    __syncthreads();
    int* ph = parthist + (size_t)bid * 4096;
#pragma unroll
    for (int i = 0; i < 4; ++i) ph[t + i * 1024] = lh[t + i * 1024];
}

// ---------------------------------------------------------------------------
// K2: per-(graph,dst) prefix over the 64 block-partials. 32768 threads
// (128 blocks) -> full-GPU TLP for the serial 64-step column walk.
// (R11 lesson: fusing this into 8 blocks = 1% occupancy = +40 us.)
__global__ __launch_bounds__(256) void colsum_kernel(int* __restrict__ parthist,
                                                     int* __restrict__ counts) {
    int t = blockIdx.x * 256 + threadIdx.x;   // [0, 32768)
    int g = t >> 12;
    int dst = t & 4095;
    int run = 0;
    for (int j = 0; j < 64; ++j) {
        int* p = parthist + (size_t)(j * 8 + g) * 4096 + dst;
        int c = *p;
        *p = run;
        run += c;
    }
    counts[g * N + dst] = run;
}

// ---------------------------------------------------------------------------
// K3: per-graph exclusive scan of counts -> CSR offsets; dinv = rsqrt(deg+1)
__global__ __launch_bounds__(1024) void scan_kernel(const int* __restrict__ counts,
                                                    int* __restrict__ offs,
                                                    float* __restrict__ dinv) {
    __shared__ int lds[1024];
    int b = blockIdx.x, t = threadIdx.x;
    int base = b * N + t * 4;
    int c0 = counts[base + 0];
    int c1 = counts[base + 1];
    int c2 = counts[base + 2];
    int c3 = counts[base + 3];
    lds[t] = c0 + c1 + c2 + c3;
    __syncthreads();
    for (int s = 1; s < 1024; s <<= 1) {
        int v = 0;
        if (t >= s) v = lds[t - s];
        __syncthreads();
        lds[t] += v;
        __syncthreads();
    }
    int excl = (t == 0) ? 0 : lds[t - 1];
    int ob = b * (N + 1) + t * 4;
    offs[ob + 0] = excl;
    offs[ob + 1] = excl + c0;
    offs[ob + 2] = excl + c0 + c1;
    offs[ob + 3] = excl + c0 + c1 + c2;
    if (t == 1023) offs[b * (N + 1) + N] = lds[1023];
    dinv[base + 0] = rsqrtf((float)(c0 + 1));
    dinv[base + 1] = rsqrtf((float)(c1 + 1));
    dinv[base + 2] = rsqrtf((float)(c2 + 1));
    dinv[base + 3] = rsqrtf((float)(c3 + 1));
}

// ---------------------------------------------------------------------------
// K4 (mega): block-range dispatch of three independent post-scan jobs:
//   [0,8192)      xconv: y1 = dinv[row]*x (f32->bf16), XCD-pinned
//   [8192,12288)  fill : scatter edge srcs into CSR (atomic-free; slot =
//                        offs[dst] + parthist[blk][dst] + local rank)
//   [12288,12416) prep_w: W[K][N] f32 -> Wt[N][K] bf16 for both layers
__global__ __launch_bounds__(256) void mega_kernel(const int* __restrict__ ei,
                                                   const int* __restrict__ offs,
                                                   const int* __restrict__ rankp,
                                                   const int* __restrict__ parthist,
                                                   int* __restrict__ csr,
                                                   const float* __restrict__ x,
                                                   unsigned short* __restrict__ xb,
                                                   const float* __restrict__ dinv,
                                                   const float* __restrict__ W1,
                                                   const float* __restrict__ W2,
                                                   unsigned short* __restrict__ Wt1,
                                                   unsigned short* __restrict__ Wt2) {
    int bid = blockIdx.x;
    int tid = threadIdx.x;
    if (bid < 8192) {
        // --- xconv ---
        int g = bid & 7;
        int off = bid >> 3;                          // [0,1024)
        size_t base = (size_t)g * (N * C) + (size_t)off * 1024 + tid * 4;
        float dv = dinv[g * N + off * 4 + (tid >> 6)];
        float4 v = *(const float4*)(x + base);
        ushort4 o;
        o.x = f2bf(dv * v.x); o.y = f2bf(dv * v.y);
        o.z = f2bf(dv * v.z); o.w = f2bf(dv * v.w);
        *(ushort4*)(xb + base) = o;
    } else if (bid < 12288) {
        // --- fill ---
        int b2 = bid - 8192;
        int g = b2 & 7;
        int e = (b2 >> 3) * 256 + tid;
        int src = ei[(size_t)g * 2 * E + e];
        int pk = rankp[(size_t)g * E + e];
        int dst = pk & 4095;
        int lr = pk >> 12;
        int blk = e >> 11;
        int bb = parthist[(size_t)(blk * 8 + g) * 4096 + dst];
        csr[(size_t)g * E + offs[g * (N + 1) + dst] + bb + lr] = src;
    } else {
        // --- prep_w ---
        int f = (bid - 12288) * 256 + tid;           // [0, 32768)
        int w = f >> 14;                             // 0: W1, 1: W2
        int idx = f & 16383;
        int n = idx >> 6;
        int ln = idx & 63;
        const float* W = w ? W2 : W1;
        unsigned short* Wt = w ? Wt2 : Wt1;
#pragma unroll
        for (int i = 0; i < 4; ++i) {
            int k = ln + i * 64;
            Wt[n * 256 + k] = f2bf(W[k * 256 + n]);
        }
    }
}

// ---------------------------------------------------------------------------
// K5: norm-free aggregation — R12 loop body exactly (best measured), but
// 128-thread workgroups with TWO INDEPENDENT WAVES (one node each):
// if the 64-thr config was workgroup-slot-capped (~8 WGs/CU -> 25% occ,
// R13 evidence), this doubles waves/CU at identical per-wave code.
//   out[b,v,:] = dinv[v] * ( y[b,v,:] + sum_{u->v} y[b,u,:] )
// Lanes 0-31 take even edges, 32-63 odd; CSR pointer pre-offset by `half`.
__global__ __launch_bounds__(128) void agg_sum(const unsigned short* __restrict__ in,
                                               unsigned short* __restrict__ out,
                                               const int* __restrict__ csr,
                                               const int* __restrict__ offs,
                                               const float* __restrict__ dinv) {
    int bid = blockIdx.x;                 // 16384
    int b = bid & 7;                      // XCD-pinned graph
    int v = (bid >> 3) * 2 + (threadIdx.x >> 6);   // wave's node
    int lane = threadIdx.x & 63;
    int half = lane >> 5;                 // 0: even edge of pair, 1: odd
    int hl = lane & 31;                   // channels [hl*8, hl*8+8)
    const unsigned short* inb = in + (size_t)b * (N * C);
    const char* base = (const char*)(inb + hl * 8);
    const int* cs2 = csr + (size_t)b * E + half;   // cs2[2*j] = edge (j,half)

    float dv = dinv[b * N + v];           // hoisted
    int s = offs[b * (N + 1) + v];
    int e = offs[b * (N + 1) + v + 1];
    const int* ip0 = cs2 + s;

    float2 acc[4];
    {   // self-loop term: lower half only (upper half zeros to avoid double count)
        uint4 xv = *(const uint4*)(inb + (size_t)v * C + hl * 8);
        if (half) {
            acc[0] = acc[1] = acc[2] = acc[3] = make_float2(0.f, 0.f);
        } else {
            acc[0] = unpk(xv.x); acc[1] = unpk(xv.y);
            acc[2] = unpk(xv.z); acc[3] = unpk(xv.w);
        }
    }

    int np = (e - s) >> 1;               // edge pairs
    int ip = 0;
    if (np >= 8) {
        int u[8];
#pragma unroll
        for (int j = 0; j < 8; ++j) u[j] = ip0[2 * j];
        for (; ip + 16 <= np; ip += 8) {
            uint4 f[8];
#pragma unroll
            for (int j = 0; j < 8; ++j)
                f[j] = *(const uint4*)(base + ((size_t)(unsigned)u[j] << 9));
#pragma unroll
            for (int j = 0; j < 8; ++j) u[j] = ip0[2 * (ip + 8 + j)];
#pragma unroll
            for (int j = 0; j < 8; ++j) accb(acc, f[j]);
        }
        {   // drain last preloaded batch
            uint4 f[8];
#pragma unroll
            for (int j = 0; j < 8; ++j)
                f[j] = *(const uint4*)(base + ((size_t)(unsigned)u[j] << 9));
#pragma unroll
            for (int j = 0; j < 8; ++j) accb(acc, f[j]);
            ip += 8;
        }
    }
    if (ip + 4 <= np) {                  // batched tail of 4 pairs
        int u[4];
#pragma unroll
        for (int j = 0; j < 4; ++j) u[j] = ip0[2 * (ip + j)];
        uint4 f[4];
#pragma unroll
        for (int j = 0; j < 4; ++j)
            f[j] = *(const uint4*)(base + ((size_t)(unsigned)u[j] << 9));
#pragma unroll
        for (int j = 0; j < 4; ++j) accb(acc, f[j]);
        ip += 4;
    }
    for (; ip < np; ++ip) {
        int u = ip0[2 * ip];
        uint4 f = *(const uint4*)(base + ((size_t)(unsigned)u << 9));
        accb(acc, f);
    }
    if (((e - s) & 1) && !half) {        // odd tail edge: lower half only
        int u = ip0[2 * np];             // = cs[e-1] (half==0)
        uint4 f = *(const uint4*)(base + ((size_t)(unsigned)u << 9));
        accb(acc, f);
    }

    // combine halves
#pragma unroll
    for (int c = 0; c < 4; ++c) {
        acc[c].x += __shfl_xor(acc[c].x, 32, 64);
        acc[c].y += __shfl_xor(acc[c].y, 32, 64);
    }

    if (!half) {
        ushort4 o01, o23;
        o01.x = f2bf(dv * acc[0].x); o01.y = f2bf(dv * acc[0].y);
        o01.z = f2bf(dv * acc[1].x); o01.w = f2bf(dv * acc[1].y);
        o23.x = f2bf(dv * acc[2].x); o23.y = f2bf(dv * acc[2].y);
        o23.z = f2bf(dv * acc[3].x); o23.w = f2bf(dv * acc[3].y);
        unsigned short* op = out + ((size_t)b * N + v) * C + hl * 8;
        *(ushort4*)(op) = o01;
        *(ushort4*)(op + 4) = o23;
    }
}

// ---------------------------------------------------------------------------
// K6: bf16 MFMA GEMM with async stage split. Single 24 KB buffer -> 4 blocks/CU.
// Cout[M,256] = A[M,256]@W[256,256] (+bias, opt ReLU, opt row-scale by dinv).
// A bf16 row-major; Wt bf16 TRANSPOSED [N][K]. LDS XOR-swizzled.
// C/D layout (HW-verified): col = lane&15, row = (lane>>4)*4 + reg.
template <bool RELU, bool BF16OUT, bool SCALE>
__global__ __launch_bounds__(256) void gemm_mfma(const unsigned short* __restrict__ A,
                                                 const unsigned short* __restrict__ Wt,
                                                 const float* __restrict__ bias,
                                                 const float* __restrict__ dinv,
                                                 void* __restrict__ Cout) {
    __shared__ __align__(16) char lds[24576];
    char* AsB = lds;            // 16 KB: [128 m][64 k] bf16, swizzled
    char* WsB = lds + 16384;    //  8 KB: [64 n][64 k] bf16, swizzled

    int tid = threadIdx.x;
    int bid = blockIdx.x;
    int g = bid & 7;                 // XCD-pinned graph
    int i = bid >> 3;                // [0,128)
    int mloc = i >> 2;               // [0,32)
    int nb = i & 3;                  // [0,4)
    int bm = g * 4096 + mloc * 128;
    int bn = nb * 64;

    const int l = tid & 63;
    const int w = tid >> 6;
    const int lr = l & 15;
    const int lg = l >> 4;

    const int arow = tid >> 3, aslot = tid & 7;
    const int wrow = tid >> 3, wslot = tid & 7;

    f32x4 acc[2][4] = {};

    // ---- prologue: stage kc = 0 synchronously ----
#pragma unroll
    for (int c = 0; c < 4; ++c) {
        int row = arow + c * 32;
        s16x8 vv = *(const s16x8*)(A + (size_t)(bm + row) * 256 + aslot * 8);
        *(s16x8*)(AsB + row * 128 + ((aslot * 16) ^ ((row & 7) << 4))) = vv;
    }
#pragma unroll
    for (int c = 0; c < 2; ++c) {
        int r = wrow + c * 32;
        s16x8 vv = *(const s16x8*)(Wt + (size_t)(bn + r) * 256 + wslot * 8);
        *(s16x8*)(WsB + r * 128 + ((wslot * 16) ^ ((r & 7) << 4))) = vv;
    }
    __syncthreads();

#pragma unroll
    for (int kc = 0; kc < 4; ++kc) {
        s16x8 pa0, pa1, pa2, pa3, pw0, pw1;
        if (kc < 3) {
            int ko = (kc + 1) * 64;
            pa0 = *(const s16x8*)(A + (size_t)(bm + arow +  0) * 256 + ko + aslot * 8);
            pa1 = *(const s16x8*)(A + (size_t)(bm + arow + 32) * 256 + ko + aslot * 8);
            pa2 = *(const s16x8*)(A + (size_t)(bm + arow + 64) * 256 + ko + aslot * 8);
            pa3 = *(const s16x8*)(A + (size_t)(bm + arow + 96) * 256 + ko + aslot * 8);
            pw0 = *(const s16x8*)(Wt + (size_t)(bn + wrow +  0) * 256 + ko + wslot * 8);
            pw1 = *(const s16x8*)(Wt + (size_t)(bn + wrow + 32) * 256 + ko + wslot * 8);
        }

#pragma unroll
        for (int ks = 0; ks < 2; ++ks) {
            s16x8 af[2];
#pragma unroll
            for (int m = 0; m < 2; ++m) {
                int row = w * 32 + m * 16 + lr;
                int bir = ks * 64 + lg * 16;
                af[m] = *(const s16x8*)(AsB + row * 128 + (bir ^ ((row & 7) << 4)));
            }
            s16x8 wf[4];
#pragma unroll
            for (int n = 0; n < 4; ++n) {
                int cidx = n * 16 + lr;
                int bir = ks * 64 + lg * 16;
                wf[n] = *(const s16x8*)(WsB + cidx * 128 + (bir ^ ((cidx & 7) << 4)));
            }
#pragma unroll
            for (int m = 0; m < 2; ++m)
#pragma unroll
                for (int n = 0; n < 4; ++n)
                    acc[m][n] = __builtin_amdgcn_mfma_f32_16x16x32_bf16(af[m], wf[n], acc[m][n], 0, 0, 0);
        }
        __syncthreads();

        if (kc < 3) {
            {
                int row = arow;
                *(s16x8*)(AsB + row * 128 + ((aslot * 16) ^ ((row & 7) << 4))) = pa0;
                row = arow + 32;
                *(s16x8*)(AsB + row * 128 + ((aslot * 16) ^ ((row & 7) << 4))) = pa1;
                row = arow + 64;
                *(s16x8*)(AsB + row * 128 + ((aslot * 16) ^ ((row & 7) << 4))) = pa2;
                row = arow + 96;
                *(s16x8*)(AsB + row * 128 + ((aslot * 16) ^ ((row & 7) << 4))) = pa3;
            }
            {
                int r = wrow;
                *(s16x8*)(WsB + r * 128 + ((wslot * 16) ^ ((r & 7) << 4))) = pw0;
                r = wrow + 32;
                *(s16x8*)(WsB + r * 128 + ((wslot * 16) ^ ((r & 7) << 4))) = pw1;
            }
            __syncthreads();
        }
    }

    // Epilogue: D col = lane&15, row = (lane>>4)*4 + reg
#pragma unroll
    for (int m = 0; m < 2; ++m) {
        int base_row = bm + w * 32 + m * 16 + lg * 4;
        float4 dv4 = make_float4(1.f, 1.f, 1.f, 1.f);
        if (SCALE) dv4 = *(const float4*)(dinv + base_row);
        float dvr[4] = {dv4.x, dv4.y, dv4.z, dv4.w};
#pragma unroll
        for (int n = 0; n < 4; ++n) {
            int col = bn + n * 16 + lr;
            float bb = bias[col];
            f32x4 v = acc[m][n];
#pragma unroll
            for (int r = 0; r < 4; ++r) {
                float o = v[r] + bb;
                if (RELU) o = fmaxf(o, 0.f);
                if (SCALE) o *= dvr[r];
                if (BF16OUT)
                    ((unsigned short*)Cout)[(size_t)(base_row + r) * 256 + col] = f2bf(o);
                else
                    ((float*)Cout)[(size_t)(base_row + r) * 256 + col] = o;
            }
        }
    }
}

// ---------------------------------------------------------------------------
extern "C" void kernel_launch(void* const* d_in, const int* in_sizes, int n_in,
                              void* d_out, int out_size, void* d_ws, size_t ws_size,
                              hipStream_t stream) {
    const float* x  = (const float*)d_in[0];
    const int*   ei = (const int*)d_in[1];
    const float* W1 = (const float*)d_in[2];
    const float* b1 = (const float*)d_in[3];
    const float* W2 = (const float*)d_in[4];
    const float* b2 = (const float*)d_in[5];
    float* out = (float*)d_out;

    char* w = (char*)d_ws;
    float* dinv            = (float*)(w + 0x0);        // 128 KB
    int*   counts          = (int*)  (w + 0x20000);    // 128 KB
    int*   offs            = (int*)  (w + 0x60000);    // ~128 KB
    int*   csr             = (int*)  (w + 0x90000);    // 4 MB
    unsigned short* Wt1    = (unsigned short*)(w + 0x4A0000);   // 128 KB
    unsigned short* Wt2    = (unsigned short*)(w + 0x4C0000);   // 128 KB
    unsigned short* xb     = (unsigned short*)(w + 0x500000);   // 16 MB (y1)
    unsigned short* bufA   = (unsigned short*)(w + 0x1500000);  // 16 MB
    unsigned short* bufB   = (unsigned short*)(w + 0x2500000);  // 16 MB (y2)
    unsigned short* bufC   = (unsigned short*)(w + 0x3500000);  // 16 MB (ends 0x4500000)
    int*   rankp           = (int*)bufC;   // alias: dead before bufC is written (agg2)
    int*   parthist        = (int*)bufA;   // alias: 8 MB, dead before bufA is written (agg1)

    hist_kernel<<<512, 1024, 0, stream>>>(ei, parthist, rankp);
    colsum_kernel<<<128, 256, 0, stream>>>(parthist, counts);
    scan_kernel<<<B, 1024, 0, stream>>>(counts, offs, dinv);
    mega_kernel<<<12416, 256, 0, stream>>>(ei, offs, rankp, parthist, csr,
                                           x, xb, dinv, W1, W2, Wt1, Wt2);

    // layer 1: agg(y1) -> bufA ; y2 = dinv*relu(bufA@W1+b1) -> bufB
    agg_sum<<<16384, 128, 0, stream>>>(xb, bufA, csr, offs, dinv);
    gemm_mfma<true, true, true><<<1024, 256, 0, stream>>>(bufA, Wt1, b1, dinv, bufB);
    // layer 2: agg(y2) -> bufC ; bufC@W2+b2 -> out (f32)
    agg_sum<<<16384, 128, 0, stream>>>(bufB, bufC, csr, offs, dinv);
    gemm_mfma<false, false, false><<<1024, 256, 0, stream>>>(bufC, Wt2, b2, nullptr, out);
}

// Round 16
// 122.329 us; speedup vs baseline: 1.1235x; 1.0572x over previous
//
#include <hip/hip_runtime.h>

// Problem constants (from reference)
constexpr int B = 8;
constexpr int N = 4096;
constexpr int E = 131072;     // 2^17
constexpr int C = 256;
constexpr int BN_TOT = B * N; // 32768

typedef __attribute__((ext_vector_type(8))) short s16x8;
typedef __attribute__((ext_vector_type(4))) float f32x4;

__device__ __forceinline__ unsigned short f2bf(float f) {
    unsigned u = __float_as_uint(f);
    unsigned r = (u + 0x7FFFu + ((u >> 16) & 1u)) >> 16;   // RNE
    return (unsigned short)r;
}
__device__ __forceinline__ float b2f(unsigned short u) {
    return __uint_as_float(((unsigned)u) << 16);
}
// unpack 2 packed bf16 (u32) -> 2 f32: low ch = q<<16, high ch = q & 0xFFFF0000
__device__ __forceinline__ void acc2(float2& a, unsigned q) {
    a.x += __uint_as_float(q << 16);
    a.y += __uint_as_float(q & 0xFFFF0000u);
}
__device__ __forceinline__ float2 unpk(unsigned q) {
    return make_float2(__uint_as_float(q << 16), __uint_as_float(q & 0xFFFF0000u));
}
__device__ __forceinline__ void accb(float2* acc, const uint4& f) {
    acc2(acc[0], f.x); acc2(acc[1], f.y); acc2(acc[2], f.z); acc2(acc[3], f.w);
}

// ---------------------------------------------------------------------------
// K1: per-block LDS histogram of edge destinations. 64 blocks per graph,
// 2048 edges each. LDS atomicAdd's return value IS the edge's local rank
// within (block, dst) -> rankp = dst | lr<<12 (lr < 2048 fits).
// Partial histograms stored as u16 (max count/block = 2048 fits).
__global__ __launch_bounds__(1024) void hist_kernel(const int* __restrict__ ei,
                                                    unsigned short* __restrict__ parthist,
                                                    int* __restrict__ rankp) {
    __shared__ int lh[4096];
    int bid = blockIdx.x;          // 512
    int g = bid & 7;               // XCD-pinned graph
    int blk = bid >> 3;            // [0,64)
    int t = threadIdx.x;
#pragma unroll
    for (int i = 0; i < 4; ++i) lh[t + i * 1024] = 0;
    __syncthreads();
    const int* dsts = ei + (size_t)g * 2 * E + E + blk * 2048;
    int e0 = blk * 2048 + t;
    int d0 = dsts[t];
    int r0 = atomicAdd(&lh[d0], 1);
    rankp[(size_t)g * E + e0] = d0 | (r0 << 12);
    int d1 = dsts[t + 1024];
    int r1 = atomicAdd(&lh[d1], 1);
    rankp[(size_t)g * E + e0 + 1024] = d1 | (r1 << 12);
    __syncthreads();
    unsigned short* ph = parthist + (size_t)bid * 4096;
#pragma unroll
    for (int i = 0; i < 4; ++i) ph[t + i * 1024] = (unsigned short)lh[t + i * 1024];
}

// ---------------------------------------------------------------------------
// K2: per-(graph,dst) prefix over the 64 block-partials (u16). 32768 threads
// (128 blocks) -> full-GPU TLP for the serial 64-step column walk.
// (R11 lesson: fusing this into 8 blocks = 1% occupancy = +40 us.)
__global__ __launch_bounds__(256) void colsum_kernel(unsigned short* __restrict__ parthist,
                                                     int* __restrict__ counts) {
    int t = blockIdx.x * 256 + threadIdx.x;   // [0, 32768)
    int g = t >> 12;
    int dst = t & 4095;
    int run = 0;
    for (int j = 0; j < 64; ++j) {
        unsigned short* p = parthist + (size_t)(j * 8 + g) * 4096 + dst;
        int c = *p;
        *p = (unsigned short)run;     // column totals < 65536 (deg ~32+slack)
        run += c;
    }
    counts[g * N + dst] = run;
}

// ---------------------------------------------------------------------------
// K3: per-graph exclusive scan of counts -> CSR offsets; dinv = rsqrt(deg+1)
__global__ __launch_bounds__(1024) void scan_kernel(const int* __restrict__ counts,
                                                    int* __restrict__ offs,
                                                    float* __restrict__ dinv) {
    __shared__ int lds[1024];
    int b = blockIdx.x, t = threadIdx.x;
    int base = b * N + t * 4;
    int c0 = counts[base + 0];
    int c1 = counts[base + 1];
    int c2 = counts[base + 2];
    int c3 = counts[base + 3];
    lds[t] = c0 + c1 + c2 + c3;
    __syncthreads();
    for (int s = 1; s < 1024; s <<= 1) {
        int v = 0;
        if (t >= s) v = lds[t - s];
        __syncthreads();
        lds[t] += v;
        __syncthreads();
    }
    int excl = (t == 0) ? 0 : lds[t - 1];
    int ob = b * (N + 1) + t * 4;
    offs[ob + 0] = excl;
    offs[ob + 1] = excl + c0;
    offs[ob + 2] = excl + c0 + c1;
    offs[ob + 3] = excl + c0 + c1 + c2;
    if (t == 1023) offs[b * (N + 1) + N] = lds[1023];
    dinv[base + 0] = rsqrtf((float)(c0 + 1));
    dinv[base + 1] = rsqrtf((float)(c1 + 1));
    dinv[base + 2] = rsqrtf((float)(c2 + 1));
    dinv[base + 3] = rsqrtf((float)(c3 + 1));
}

// ---------------------------------------------------------------------------
// K4 (mega): block-range dispatch of three independent post-scan jobs:
//   [0,8192)      xconv: y1 = dinv[row]*x (f32->bf16), XCD-pinned
//   [8192,12288)  fill : scatter edge srcs into CSR (atomic-free; slot =
//                        offs[dst] + parthist[blk][dst] + local rank)
//   [12288,12416) prep_w: W[K][N] f32 -> Wt[N][K] bf16 for both layers
__global__ __launch_bounds__(256) void mega_kernel(const int* __restrict__ ei,
                                                   const int* __restrict__ offs,
                                                   const int* __restrict__ rankp,
                                                   const unsigned short* __restrict__ parthist,
                                                   int* __restrict__ csr,
                                                   const float* __restrict__ x,
                                                   unsigned short* __restrict__ xb,
                                                   const float* __restrict__ dinv,
                                                   const float* __restrict__ W1,
                                                   const float* __restrict__ W2,
                                                   unsigned short* __restrict__ Wt1,
                                                   unsigned short* __restrict__ Wt2) {
    int bid = blockIdx.x;
    int tid = threadIdx.x;
    if (bid < 8192) {
        // --- xconv ---
        int g = bid & 7;
        int off = bid >> 3;                          // [0,1024)
        size_t base = (size_t)g * (N * C) + (size_t)off * 1024 + tid * 4;
        float dv = dinv[g * N + off * 4 + (tid >> 6)];
        float4 v = *(const float4*)(x + base);
        ushort4 o;
        o.x = f2bf(dv * v.x); o.y = f2bf(dv * v.y);
        o.z = f2bf(dv * v.z); o.w = f2bf(dv * v.w);
        *(ushort4*)(xb + base) = o;
    } else if (bid < 12288) {
        // --- fill ---
        int b2 = bid - 8192;
        int g = b2 & 7;
        int e = (b2 >> 3) * 256 + tid;
        int src = ei[(size_t)g * 2 * E + e];
        int pk = rankp[(size_t)g * E + e];
        int dst = pk & 4095;
        int lr = pk >> 12;
        int blk = e >> 11;
        int bb = parthist[(size_t)(blk * 8 + g) * 4096 + dst];
        csr[(size_t)g * E + offs[g * (N + 1) + dst] + bb + lr] = src;
    } else {
        // --- prep_w ---
        int f = (bid - 12288) * 256 + tid;           // [0, 32768)
        int w = f >> 14;                             // 0: W1, 1: W2
        int idx = f & 16383;
        int n = idx >> 6;
        int ln = idx & 63;
        const float* W = w ? W2 : W1;
        unsigned short* Wt = w ? Wt2 : Wt1;
#pragma unroll
        for (int i = 0; i < 4; ++i) {
            int k = ln + i * 64;
            Wt[n * 256 + k] = f2bf(W[k * 256 + n]);
        }
    }
}

// ---------------------------------------------------------------------------
// K5: norm-free aggregation — R12 champion config exactly: ONE WAVE PER
// WORKGROUP (64 thr), one node per wave, lean streaming 8-pair pipeline.
// (R13 preload: VGPR 72 -> 25% occ, -9%. R14 strips: serialized chains, -5%.
//  R15 128-thr: -3%. Agg is L2 random-row-gather bound at ~35 us; scheduling
//  shape does not move it.)
//   out[b,v,:] = dinv[v] * ( y[b,v,:] + sum_{u->v} y[b,u,:] )
// Lanes 0-31 take even edges, 32-63 odd; CSR pointer pre-offset by `half`.
__global__ __launch_bounds__(64) void agg_sum(const unsigned short* __restrict__ in,
                                              unsigned short* __restrict__ out,
                                              const int* __restrict__ csr,
                                              const int* __restrict__ offs,
                                              const float* __restrict__ dinv) {
    int bid = blockIdx.x;                 // 32768
    int b = bid & 7;                      // XCD-pinned graph
    int v = bid >> 3;                     // [0,4096)
    int lane = threadIdx.x;               // [0,64)
    int half = lane >> 5;                 // 0: even edge of pair, 1: odd
    int hl = lane & 31;                   // channels [hl*8, hl*8+8)
    const unsigned short* inb = in + (size_t)b * (N * C);
    const char* base = (const char*)(inb + hl * 8);
    const int* cs2 = csr + (size_t)b * E + half;   // cs2[2*j] = edge (j,half)

    float dv = dinv[b * N + v];           // hoisted
    int s = offs[b * (N + 1) + v];
    int e = offs[b * (N + 1) + v + 1];
    const int* ip0 = cs2 + s;

    float2 acc[4];
    {   // self-loop term: lower half only (upper half zeros to avoid double count)
        uint4 xv = *(const uint4*)(inb + (size_t)v * C + hl * 8);
        if (half) {
            acc[0] = acc[1] = acc[2] = acc[3] = make_float2(0.f, 0.f);
        } else {
            acc[0] = unpk(xv.x); acc[1] = unpk(xv.y);
            acc[2] = unpk(xv.z); acc[3] = unpk(xv.w);
        }
    }

    int np = (e - s) >> 1;               // edge pairs
    int ip = 0;
    if (np >= 8) {
        int u[8];
#pragma unroll
        for (int j = 0; j < 8; ++j) u[j] = ip0[2 * j];
        for (; ip + 16 <= np; ip += 8) {
            uint4 f[8];
#pragma unroll
            for (int j = 0; j < 8; ++j)
                f[j] = *(const uint4*)(base + ((size_t)(unsigned)u[j] << 9));
#pragma unroll
            for (int j = 0; j < 8; ++j) u[j] = ip0[2 * (ip + 8 + j)];
#pragma unroll
            for (int j = 0; j < 8; ++j) accb(acc, f[j]);
        }
        {   // drain last preloaded batch
            uint4 f[8];
#pragma unroll
            for (int j = 0; j < 8; ++j)
                f[j] = *(const uint4*)(base + ((size_t)(unsigned)u[j] << 9));
#pragma unroll
            for (int j = 0; j < 8; ++j) accb(acc, f[j]);
            ip += 8;
        }
    }
    if (ip + 4 <= np) {                  // batched tail of 4 pairs
        int u[4];
#pragma unroll
        for (int j = 0; j < 4; ++j) u[j] = ip0[2 * (ip + j)];
        uint4 f[4];
#pragma unroll
        for (int j = 0; j < 4; ++j)
            f[j] = *(const uint4*)(base + ((size_t)(unsigned)u[j] << 9));
#pragma unroll
        for (int j = 0; j < 4; ++j) accb(acc, f[j]);
        ip += 4;
    }
    for (; ip < np; ++ip) {
        int u = ip0[2 * ip];
        uint4 f = *(const uint4*)(base + ((size_t)(unsigned)u << 9));
        accb(acc, f);
    }
    if (((e - s) & 1) && !half) {        // odd tail edge: lower half only
        int u = ip0[2 * np];             // = cs[e-1] (half==0)
        uint4 f = *(const uint4*)(base + ((size_t)(unsigned)u << 9));
        accb(acc, f);
    }

    // combine halves
#pragma unroll
    for (int c = 0; c < 4; ++c) {
        acc[c].x += __shfl_xor(acc[c].x, 32, 64);
        acc[c].y += __shfl_xor(acc[c].y, 32, 64);
    }

    if (!half) {
        ushort4 o01, o23;
        o01.x = f2bf(dv * acc[0].x); o01.y = f2bf(dv * acc[0].y);
        o01.z = f2bf(dv * acc[1].x); o01.w = f2bf(dv * acc[1].y);
        o23.x = f2bf(dv * acc[2].x); o23.y = f2bf(dv * acc[2].y);
        o23.z = f2bf(dv * acc[3].x); o23.w = f2bf(dv * acc[3].y);
        unsigned short* op = out + ((size_t)b * N + v) * C + hl * 8;
        *(ushort4*)(op) = o01;
        *(ushort4*)(op + 4) = o23;
    }
}

// ---------------------------------------------------------------------------
// K6: bf16 MFMA GEMM with async stage split. Single 24 KB buffer -> 4 blocks/CU.
// Cout[M,256] = A[M,256]@W[256,256] (+bias, opt ReLU, opt row-scale by dinv).
// A bf16 row-major; Wt bf16 TRANSPOSED [N][K]. LDS XOR-swizzled.
// C/D layout (HW-verified): col = lane&15, row = (lane>>4)*4 + reg.
template <bool RELU, bool BF16OUT, bool SCALE>
__global__ __launch_bounds__(256) void gemm_mfma(const unsigned short* __restrict__ A,
                                                 const unsigned short* __restrict__ Wt,
                                                 const float* __restrict__ bias,
                                                 const float* __restrict__ dinv,
                                                 void* __restrict__ Cout) {
    __shared__ __align__(16) char lds[24576];
    char* AsB = lds;            // 16 KB: [128 m][64 k] bf16, swizzled
    char* WsB = lds + 16384;    //  8 KB: [64 n][64 k] bf16, swizzled

    int tid = threadIdx.x;
    int bid = blockIdx.x;
    int g = bid & 7;                 // XCD-pinned graph
    int i = bid >> 3;                // [0,128)
    int mloc = i >> 2;               // [0,32)
    int nb = i & 3;                  // [0,4)
    int bm = g * 4096 + mloc * 128;
    int bn = nb * 64;

    const int l = tid & 63;
    const int w = tid >> 6;
    const int lr = l & 15;
    const int lg = l >> 4;

    const int arow = tid >> 3, aslot = tid & 7;
    const int wrow = tid >> 3, wslot = tid & 7;

    f32x4 acc[2][4] = {};

    // ---- prologue: stage kc = 0 synchronously ----
#pragma unroll
    for (int c = 0; c < 4; ++c) {
        int row = arow + c * 32;
        s16x8 vv = *(const s16x8*)(A + (size_t)(bm + row) * 256 + aslot * 8);
        *(s16x8*)(AsB + row * 128 + ((aslot * 16) ^ ((row & 7) << 4))) = vv;
    }
#pragma unroll
    for (int c = 0; c < 2; ++c) {
        int r = wrow + c * 32;
        s16x8 vv = *(const s16x8*)(Wt + (size_t)(bn + r) * 256 + wslot * 8);
        *(s16x8*)(WsB + r * 128 + ((wslot * 16) ^ ((r & 7) << 4))) = vv;
    }
    __syncthreads();

#pragma unroll
    for (int kc = 0; kc < 4; ++kc) {
        s16x8 pa0, pa1, pa2, pa3, pw0, pw1;
        if (kc < 3) {
            int ko = (kc + 1) * 64;
            pa0 = *(const s16x8*)(A + (size_t)(bm + arow +  0) * 256 + ko + aslot * 8);
            pa1 = *(const s16x8*)(A + (size_t)(bm + arow + 32) * 256 + ko + aslot * 8);
            pa2 = *(const s16x8*)(A + (size_t)(bm + arow + 64) * 256 + ko + aslot * 8);
            pa3 = *(const s16x8*)(A + (size_t)(bm + arow + 96) * 256 + ko + aslot * 8);
            pw0 = *(const s16x8*)(Wt + (size_t)(bn + wrow +  0) * 256 + ko + wslot * 8);
            pw1 = *(const s16x8*)(Wt + (size_t)(bn + wrow + 32) * 256 + ko + wslot * 8);
        }

#pragma unroll
        for (int ks = 0; ks < 2; ++ks) {
            s16x8 af[2];
#pragma unroll
            for (int m = 0; m < 2; ++m) {
                int row = w * 32 + m * 16 + lr;
                int bir = ks * 64 + lg * 16;
                af[m] = *(const s16x8*)(AsB + row * 128 + (bir ^ ((row & 7) << 4)));
            }
            s16x8 wf[4];
#pragma unroll
            for (int n = 0; n < 4; ++n) {
                int cidx = n * 16 + lr;
                int bir = ks * 64 + lg * 16;
                wf[n] = *(const s16x8*)(WsB + cidx * 128 + (bir ^ ((cidx & 7) << 4)));
            }
#pragma unroll
            for (int m = 0; m < 2; ++m)
#pragma unroll
                for (int n = 0; n < 4; ++n)
                    acc[m][n] = __builtin_amdgcn_mfma_f32_16x16x32_bf16(af[m], wf[n], acc[m][n], 0, 0, 0);
        }
        __syncthreads();

        if (kc < 3) {
            {
                int row = arow;
                *(s16x8*)(AsB + row * 128 + ((aslot * 16) ^ ((row & 7) << 4))) = pa0;
                row = arow + 32;
                *(s16x8*)(AsB + row * 128 + ((aslot * 16) ^ ((row & 7) << 4))) = pa1;
                row = arow + 64;
                *(s16x8*)(AsB + row * 128 + ((aslot * 16) ^ ((row & 7) << 4))) = pa2;
                row = arow + 96;
                *(s16x8*)(AsB + row * 128 + ((aslot * 16) ^ ((row & 7) << 4))) = pa3;
            }
            {
                int r = wrow;
                *(s16x8*)(WsB + r * 128 + ((wslot * 16) ^ ((r & 7) << 4))) = pw0;
                r = wrow + 32;
                *(s16x8*)(WsB + r * 128 + ((wslot * 16) ^ ((r & 7) << 4))) = pw1;
            }
            __syncthreads();
        }
    }

    // Epilogue: D col = lane&15, row = (lane>>4)*4 + reg
#pragma unroll
    for (int m = 0; m < 2; ++m) {
        int base_row = bm + w * 32 + m * 16 + lg * 4;
        float4 dv4 = make_float4(1.f, 1.f, 1.f, 1.f);
        if (SCALE) dv4 = *(const float4*)(dinv + base_row);
        float dvr[4] = {dv4.x, dv4.y, dv4.z, dv4.w};
#pragma unroll
        for (int n = 0; n < 4; ++n) {
            int col = bn + n * 16 + lr;
            float bb = bias[col];
            f32x4 v = acc[m][n];
#pragma unroll
            for (int r = 0; r < 4; ++r) {
                float o = v[r] + bb;
                if (RELU) o = fmaxf(o, 0.f);
                if (SCALE) o *= dvr[r];
                if (BF16OUT)
                    ((unsigned short*)Cout)[(size_t)(base_row + r) * 256 + col] = f2bf(o);
                else
                    ((float*)Cout)[(size_t)(base_row + r) * 256 + col] = o;
            }
        }
    }
}

// ---------------------------------------------------------------------------
extern "C" void kernel_launch(void* const* d_in, const int* in_sizes, int n_in,
                              void* d_out, int out_size, void* d_ws, size_t ws_size,
                              hipStream_t stream) {
    const float* x  = (const float*)d_in[0];
    const int*   ei = (const int*)d_in[1];
    const float* W1 = (const float*)d_in[2];
    const float* b1 = (const float*)d_in[3];
    const float* W2 = (const float*)d_in[4];
    const float* b2 = (const float*)d_in[5];
    float* out = (float*)d_out;

    char* w = (char*)d_ws;
    float* dinv            = (float*)(w + 0x0);        // 128 KB
    int*   counts          = (int*)  (w + 0x20000);    // 128 KB
    int*   offs            = (int*)  (w + 0x60000);    // ~128 KB
    int*   csr             = (int*)  (w + 0x90000);    // 4 MB
    unsigned short* Wt1    = (unsigned short*)(w + 0x4A0000);   // 128 KB
    unsigned short* Wt2    = (unsigned short*)(w + 0x4C0000);   // 128 KB
    unsigned short* xb     = (unsigned short*)(w + 0x500000);   // 16 MB (y1)
    unsigned short* bufA   = (unsigned short*)(w + 0x1500000);  // 16 MB
    unsigned short* bufB   = (unsigned short*)(w + 0x2500000);  // 16 MB (y2)
    unsigned short* bufC   = (unsigned short*)(w + 0x3500000);  // 16 MB (ends 0x4500000)
    int*   rankp           = (int*)bufC;                 // alias: dead before bufC written
    unsigned short* parthist = (unsigned short*)bufA;    // alias: 4 MB, dead before bufA written

    hist_kernel<<<512, 1024, 0, stream>>>(ei, parthist, rankp);
    colsum_kernel<<<128, 256, 0, stream>>>(parthist, counts);
    scan_kernel<<<B, 1024, 0, stream>>>(counts, offs, dinv);
    mega_kernel<<<12416, 256, 0, stream>>>(ei, offs, rankp, parthist, csr,
                                           x, xb, dinv, W1, W2, Wt1, Wt2);

    // layer 1: agg(y1) -> bufA ; y2 = dinv*relu(bufA@W1+b1) -> bufB
    agg_sum<<<32768, 64, 0, stream>>>(xb, bufA, csr, offs, dinv);
    gemm_mfma<true, true, true><<<1024, 256, 0, stream>>>(bufA, Wt1, b1, dinv, bufB);
    // layer 2: agg(y2) -> bufC ; bufC@W2+b2 -> out (f32)
    agg_sum<<<32768, 64, 0, stream>>>(bufB, bufC, csr, offs, dinv);
    gemm_mfma<false, false, false><<<1024, 256, 0, stream>>>(bufC, Wt2, b2, nullptr, out);
}